// Round 2
// baseline (111.133 us; speedup 1.0000x reference)
//
#include <hip/hip_runtime.h>

// ---------------------------------------------------------------------------
// RandomForest: 100 trees, depth 5, D=256, B=8192, C=64.
// Two-kernel version (was four): prep and fixup folded into forest_all.
//  * forest_all: per block 256 samples x 8 trees. W converted f32->bf16 hi/lo
//    in-kernel, staged swizzled into LDS (dbuf 2x32KB, quarter-K). A converted
//    f32->bf16 hi/lo in registers (same HBM bytes as old xh/xl). 3-pass MFMA
//    (hi*hi + hi*lo + lo*hi, residual ~2^-18/term => sigma_z ~ 6e-5).
//    Near-ties (|z_path| < TAU=2e-3 ~ 33 sigma) fixed in-lane: fp64 dot of
//    only the ambiguous node(s) + re-traversal. Rare (~0.03/wave-pass).
//  * leaf_gather: reads f32 leaves directly (removes the bf16 leaf
//    quantization that dominated absmax=2^-9).
// ---------------------------------------------------------------------------

typedef __bf16 bf16;
typedef __attribute__((ext_vector_type(8))) __bf16 bf16x8;
typedef __attribute__((ext_vector_type(4))) float f32x4;

#define NTREES 100
#define NB     8192
#define ND     256
#define NNODES 31
#define NLEAF  32
#define NCLS   64
#define TAU    2.0e-3f

// Register-select traversal over the 16 node scores of one (sample, tree).
// Matches reference: d = (sigmoid(z) <= 0.5) <=> (z <= 0); idx = 2*idx + d.
// Level l reads node idx_l (nodes 0..15 only); leaf bits = d0..d4.
static __device__ __forceinline__ int traverse(const float z[16], float* mn_out) {
    float a0 = z[0];
    bool d0 = a0 <= 0.f;
    float a1 = d0 ? z[1] : z[0];
    bool d1 = a1 <= 0.f;
    float a2 = d0 ? (d1 ? z[3] : z[2]) : (d1 ? z[1] : z[0]);
    bool d2 = a2 <= 0.f;
    float m0 = d2 ? z[1] : z[0], m1 = d2 ? z[3] : z[2];
    float m2 = d2 ? z[5] : z[4], m3 = d2 ? z[7] : z[6];
    float p0 = d1 ? m1 : m0, p1 = d1 ? m3 : m2;
    float a3 = d0 ? p1 : p0;
    bool d3 = a3 <= 0.f;
    float n0 = d3 ? z[1] : z[0],  n1 = d3 ? z[3] : z[2];
    float n2 = d3 ? z[5] : z[4],  n3 = d3 ? z[7] : z[6];
    float n4 = d3 ? z[9] : z[8],  n5 = d3 ? z[11] : z[10];
    float n6 = d3 ? z[13] : z[12], n7 = d3 ? z[15] : z[14];
    float q0 = d2 ? n1 : n0, q1 = d2 ? n3 : n2;
    float q2 = d2 ? n5 : n4, q3 = d2 ? n7 : n6;
    float r0 = d1 ? q1 : q0, r1 = d1 ? q3 : q2;
    float a4 = d0 ? r1 : r0;
    bool d4 = a4 <= 0.f;
    *mn_out = fminf(fminf(fminf(fabsf(a0), fabsf(a1)),
                          fminf(fabsf(a2), fabsf(a3))), fabsf(a4));
    return ((int)d0 << 4) | ((int)d1 << 3) | ((int)d2 << 2)
         | ((int)d3 << 1) | (int)d4;
}

// ---- K1: GEMM + traversal + inline fixup ------------------------------------
// block: 256 samples x 8 trees (128 node-cols). 4 waves, each M=64, N=128.
__global__ __launch_bounds__(256, 2) void forest_all(
    const float* __restrict__ x,      // [8192][256]
    const float* __restrict__ wf,     // [100][31][256]
    const float* __restrict__ bias,   // [100][31]
    unsigned char* __restrict__ idxb) // [8192][100]
{
    __shared__ char lds[65536];        // two 32KB B buffers; scr overlays buf0

    const int tid  = threadIdx.x;
    const int wave = tid >> 6;
    const int lane = tid & 63;
    const int m    = lane & 15;
    const int q    = lane >> 4;

    const int lin  = blockIdx.x + gridDim.x * blockIdx.y;   // 0..415
    const int xcd  = lin & 7;
    const int slot = lin >> 3;         // 0..51
    const int mg   = xcd * 4 + (slot / 13);
    const int tg   = slot % 13;        // tree-group of 8 (tg 12: 4 real)

    f32x4 acc[4][8];
#pragma unroll
    for (int mi = 0; mi < 4; ++mi)
#pragma unroll
        for (int ni = 0; ni < 8; ++ni)
            acc[mi][ni] = (f32x4){0.f, 0.f, 0.f, 0.f};

    // A source: row(mi) = mg*256 + wave*64 + mi*16 + m ; dims = kk*32 + q*8
    const float* xbase = x + (size_t)(mg * 256 + wave * 64 + m) * ND + q * 8;

    // stage quarter kq of W (8 trees x 16 nodes x 64 dims) into buf as bf16
    // hi (16KB) | lo (16KB), swizzled: row*64 + (oct^(row&7))*8 elements.
    auto stage = [&](int kq, char* buf) {
#pragma unroll
        for (int it = 0; it < 4; ++it) {
            int idx = it * 256 + tid;           // 0..1023 octet tasks
            int oct = idx & 7, row = idx >> 3;  // row 0..127
            int tree = tg * 8 + (row >> 4), node = row & 15;
            f32x4 v0 = (f32x4){0.f, 0.f, 0.f, 0.f};
            f32x4 v1 = (f32x4){0.f, 0.f, 0.f, 0.f};
            if (tree < NTREES) {
                const float* src = wf + ((size_t)tree * NNODES + node) * ND
                                 + kq * 64 + oct * 8;
                v0 = *(const f32x4*)src;
                v1 = *(const f32x4*)(src + 4);
            }
            bf16x8 h8, l8;
#pragma unroll
            for (int e = 0; e < 4; ++e) {
                bf16 h0 = (bf16)v0[e];
                h8[e]     = h0; l8[e]     = (bf16)(v0[e] - (float)h0);
                bf16 h1 = (bf16)v1[e];
                h8[4 + e] = h1; l8[4 + e] = (bf16)(v1[e] - (float)h1);
            }
            int cp = oct ^ (row & 7);
            bf16* dst = (bf16*)buf + row * 64 + cp * 8;
            *(bf16x8*)dst = h8;
            *(bf16x8*)(dst + 8192) = l8;
        }
    };

    stage(0, lds);
    // A prefetch for kk=0 (raw f32; converted at consume time)
    f32x4 raw[4][2];
#pragma unroll
    for (int mi = 0; mi < 4; ++mi) {
        raw[mi][0] = *(const f32x4*)(xbase + mi * 4096);
        raw[mi][1] = *(const f32x4*)(xbase + mi * 4096 + 4);
    }
    __syncthreads();

    bf16x8 cah[4], cal[4];
#pragma unroll
    for (int kq = 0; kq < 4; ++kq) {
        const bf16* bufc = (const bf16*)(lds + (kq & 1) * 32768);
        if (kq < 3) stage(kq + 1, lds + ((kq + 1) & 1) * 32768);
#pragma unroll
        for (int kkq = 0; kkq < 2; ++kkq) {
            const int kk = kq * 2 + kkq;
            // convert current raw A -> bf16 hi/lo
#pragma unroll
            for (int mi = 0; mi < 4; ++mi) {
#pragma unroll
                for (int e = 0; e < 4; ++e) {
                    float f0 = raw[mi][0][e], f1 = raw[mi][1][e];
                    bf16 h0 = (bf16)f0, h1 = (bf16)f1;
                    cah[mi][e]     = h0; cal[mi][e]     = (bf16)(f0 - (float)h0);
                    cah[mi][4 + e] = h1; cal[mi][4 + e] = (bf16)(f1 - (float)h1);
                }
            }
            if (kk < 7) {                      // prefetch next A batch
#pragma unroll
                for (int mi = 0; mi < 4; ++mi) {
                    raw[mi][0] = *(const f32x4*)(xbase + mi * 4096 + (kk + 1) * 32);
                    raw[mi][1] = *(const f32x4*)(xbase + mi * 4096 + (kk + 1) * 32 + 4);
                }
            }
#pragma unroll
            for (int ni = 0; ni < 8; ++ni) {
                const int n  = ni * 16 + m;
                const int cp = (kkq * 4 + q) ^ (m & 7);
                bf16x8 bh = *(const bf16x8*)(bufc + n * 64 + cp * 8);
                bf16x8 bl = *(const bf16x8*)(bufc + 8192 + n * 64 + cp * 8);
#pragma unroll
                for (int mi = 0; mi < 4; ++mi) {
                    acc[mi][ni] = __builtin_amdgcn_mfma_f32_16x16x32_bf16(cal[mi], bh, acc[mi][ni], 0, 0, 0);
                    acc[mi][ni] = __builtin_amdgcn_mfma_f32_16x16x32_bf16(cah[mi], bl, acc[mi][ni], 0, 0, 0);
                    acc[mi][ni] = __builtin_amdgcn_mfma_f32_16x16x32_bf16(cah[mi], bh, acc[mi][ni], 0, 0, 0);
                }
            }
        }
        __syncthreads();   // next buffer staged AND current fully consumed
    }

    // ---- epilogue: per-wave transpose via LDS, register-select traversal,
    //      in-lane fp64 fixup of near-ties (replaces the fixup kernel).
    float biasv[8];
#pragma unroll
    for (int ni = 0; ni < 8; ++ni) {
        int tree = tg * 8 + ni;
        biasv[ni] = (tree < NTREES) ? bias[(size_t)tree * NNODES + m] : 0.f;
    }

    float* ws_ = (float*)lds + wave * 1280;    // 64 rows x 20 floats per wave
    const int sg = mg * 256 + wave * 64 + lane;
    unsigned int pk0 = 0, pk1 = 0;
#pragma unroll
    for (int ni = 0; ni < 8; ++ni) {
        // D layout: col = m (node), row-in-16 = q*4 + r (sample)
#pragma unroll
        for (int mi = 0; mi < 4; ++mi)
#pragma unroll
            for (int r = 0; r < 4; ++r)
                ws_[(mi * 16 + q * 4 + r) * 20 + m] = acc[mi][ni][r] + biasv[ni];
        f32x4 z0 = *(f32x4*)&ws_[lane * 20];
        f32x4 z1 = *(f32x4*)&ws_[lane * 20 + 4];
        f32x4 z2 = *(f32x4*)&ws_[lane * 20 + 8];
        f32x4 z3 = *(f32x4*)&ws_[lane * 20 + 12];
        float z[16] = {z0[0], z0[1], z0[2], z0[3], z1[0], z1[1], z1[2], z1[3],
                       z2[0], z2[1], z2[2], z2[3], z3[0], z3[1], z3[2], z3[3]};
        float mn;
        int leaf = traverse(z, &mn);
        const int tree = tg * 8 + ni;
        if (tree < NTREES && mn < TAU) {       // rare: ~33 sigma guard band
            // fp64 recompute of every ambiguous node among the 16, then
            // re-traverse with corrected signs. Dummy trees excluded above.
            const float* xr = x + (size_t)sg * ND;
            float zc[16];
#pragma unroll
            for (int nd = 0; nd < 16; ++nd) zc[nd] = z[nd];
#pragma unroll
            for (int nd = 0; nd < 16; ++nd) {
                if (fabsf(z[nd]) < TAU) {
                    const float* wr = wf + ((size_t)tree * NNODES + nd) * ND;
                    double s0 = 0.0, s1 = 0.0;
#pragma unroll 4
                    for (int k2 = 0; k2 < 32; ++k2) {
                        f32x4 xv = *(const f32x4*)(xr + k2 * 8);
                        f32x4 wv = *(const f32x4*)(wr + k2 * 8);
                        f32x4 xu = *(const f32x4*)(xr + k2 * 8 + 4);
                        f32x4 wu = *(const f32x4*)(wr + k2 * 8 + 4);
                        s0 += (double)xv[0] * wv[0] + (double)xv[1] * wv[1]
                            + (double)xv[2] * wv[2] + (double)xv[3] * wv[3];
                        s1 += (double)xu[0] * wu[0] + (double)xu[1] * wu[1]
                            + (double)xu[2] * wu[2] + (double)xu[3] * wu[3];
                    }
                    double zt = s0 + s1 + (double)bias[(size_t)tree * NNODES + nd];
                    zc[nd] = (zt <= 0.0) ? -1.f : 1.f;
                }
            }
            float mn2;
            leaf = traverse(zc, &mn2);
        }
        if (ni < 4) pk0 |= (unsigned)leaf << (8 * ni);
        else        pk1 |= (unsigned)leaf << (8 * (ni - 4));
    }
    unsigned char* dst = idxb + (size_t)sg * NTREES + tg * 8;
    *(unsigned int*)dst = pk0;
    if (tg < 12) *(unsigned int*)(dst + 4) = pk1;
}

// ---- K2: leaf gather (f32 leaves, no quantization) + forest mean ------------
__global__ void leaf_gather(const unsigned char* __restrict__ idxb,
                            const float* __restrict__ lv,
                            float* __restrict__ out) {
    const int wave = threadIdx.x >> 6;
    const int lane = threadIdx.x & 63;
    const int s = blockIdx.x * 4 + wave;
    unsigned int rw = 0;
    if (lane < 25) rw = *(const unsigned int*)(idxb + (size_t)s * NTREES + lane * 4);
    float acc = 0.f;
#pragma unroll 10
    for (int t = 0; t < NTREES; ++t) {
        unsigned int wrd = __shfl(rw, t >> 2);
        int li = (wrd >> ((t & 3) * 8)) & 255;
        acc += lv[((size_t)t * NLEAF + li) * NCLS + lane];
    }
    out[(size_t)s * NCLS + lane] = acc * 0.01f;
}

// ---------------------------------------------------------------------------
extern "C" void kernel_launch(void* const* d_in, const int* in_sizes, int n_in,
                              void* d_out, int out_size, void* d_ws, size_t ws_size,
                              hipStream_t stream) {
    const float* x  = (const float*)d_in[0];   // [8192,256]
    const float* nw = (const float*)d_in[1];   // [100,31,256]
    const float* nb = (const float*)d_in[2];   // [100,31]
    const float* lv = (const float*)d_in[3];   // [100,32,64]
    float* out = (float*)d_out;

    unsigned char* idxb = (unsigned char*)d_ws;            // [8192][100]
    if (ws_size < (size_t)NB * NTREES) return;

    forest_all<<<dim3(13, 32), 256, 0, stream>>>(x, nw, nb, idxb);
    leaf_gather<<<NB / 4, 256, 0, stream>>>(idxb, lv, out);
}